// Round 2
// baseline (2083.726 us; speedup 1.0000x reference)
//
#include <hip/hip_runtime.h>
#include <stdint.h>

typedef float f32x4 __attribute__((ext_vector_type(4)));
typedef int i32x4 __attribute__((ext_vector_type(4)));

#define LOG2E 1.4426950408889634f

__device__ __forceinline__ float bf2f(unsigned short u) {
  union { unsigned int i; float f; } x; x.i = ((unsigned int)u) << 16; return x.f;
}
__device__ __forceinline__ unsigned short f2bf(float f) {
  union { float f; unsigned int i; } x; x.f = f;
  unsigned int u = x.i + 0x7fffu + ((x.i >> 16) & 1u);
  return (unsigned short)(u >> 16);
}
__device__ __forceinline__ float fexp2(float x) {
#if __has_builtin(__builtin_amdgcn_exp2f)
  return __builtin_amdgcn_exp2f(x);
#else
  return exp2f(x);
#endif
}
__device__ __forceinline__ float frcp(float x) {
#if __has_builtin(__builtin_amdgcn_rcpf)
  return __builtin_amdgcn_rcpf(x);
#else
  return 1.f / x;
#endif
}
__device__ __forceinline__ float fast_exp(float x) { return fexp2(x * LOG2E); }
__device__ __forceinline__ float fast_tanh(float x) {
  float e = fexp2(x * (2.f * LOG2E));
  return 1.f - 2.f * frcp(e + 1.f);
}
__device__ __forceinline__ float fast_sigmoid(float x) {
  return frcp(1.f + fexp2(-x * LOG2E));
}

__device__ __forceinline__ void mfma_bf16_16x16x32(f32x4& d, i32x4 a, i32x4 b) {
  asm("v_mfma_f32_16x16x32_bf16 %0, %1, %2, %0" : "+v"(d) : "v"(a), "v"(b));
}

__device__ __forceinline__ void stage16(const unsigned short* g, unsigned short* lds_wave_base, int lane) {
#if __has_builtin(__builtin_amdgcn_global_load_lds)
  __builtin_amdgcn_global_load_lds(
      (const __attribute__((address_space(1))) unsigned int*)(uintptr_t)g,
      (__attribute__((address_space(3))) unsigned int*)(uintptr_t)lds_wave_base,
      16, 0, 0);
#else
  i32x4 v = *(const i32x4*)g;
  *(i32x4*)(lds_wave_base + lane * 8) = v;
#endif
}

// ---------------- LDS-staged GEMM (prologue proj + final probs) ----------------
#define BM 128
#define BN 128
#define BK 32

template <bool OUT_BF16, bool BIAS>
__device__ __forceinline__ void gemm_body(
    const unsigned short* __restrict__ A, const unsigned short* __restrict__ B,
    void* __restrict__ Cout, const float* __restrict__ bias,
    int K, int ldc, int nbound, int m0, int n0)
{
  __shared__ __align__(16) unsigned short lA[BM * BK];
  __shared__ __align__(16) unsigned short lB[BN * BK];
  const int tid = threadIdx.x;
  const int lane = tid & 63;
  const int w = tid >> 6;
  const int wm = w >> 1, wn = w & 1;
  const int frag_row = lane & 15;
  const int kgrp = lane >> 4;

  f32x4 acc[4][4];
#pragma unroll
  for (int i = 0; i < 4; ++i)
#pragma unroll
    for (int j = 0; j < 4; ++j) acc[i][j] = 0.f;

  const int nK = K / BK;
  const int c0 = tid, c1 = tid + 256;
  for (int kt = 0; kt < nK; ++kt) {
    const int kb = kt * BK;
    stage16(A + (size_t)(m0 + (c0 >> 2)) * K + kb + (c0 & 3) * 8, lA + (w * 64) * 8, lane);
    stage16(A + (size_t)(m0 + (c1 >> 2)) * K + kb + (c1 & 3) * 8, lA + (256 + w * 64) * 8, lane);
    stage16(B + (size_t)(n0 + (c0 >> 2)) * K + kb + (c0 & 3) * 8, lB + (w * 64) * 8, lane);
    stage16(B + (size_t)(n0 + (c1 >> 2)) * K + kb + (c1 & 3) * 8, lB + (256 + w * 64) * 8, lane);
    __syncthreads();

    i32x4 af[4], bfr[4];
#pragma unroll
    for (int i = 0; i < 4; ++i) {
      int ra = wm * 64 + i * 16 + frag_row;
      af[i] = *(const i32x4*)&lA[ra * BK + kgrp * 8];
      int rb = wn * 64 + i * 16 + frag_row;
      bfr[i] = *(const i32x4*)&lB[rb * BK + kgrp * 8];
    }
#pragma unroll
    for (int i = 0; i < 4; ++i)
#pragma unroll
      for (int j = 0; j < 4; ++j) mfma_bf16_16x16x32(acc[i][j], af[i], bfr[j]);
    __syncthreads();
  }

  const int crow = (lane >> 4) * 4;
  const int ccol = lane & 15;
#pragma unroll
  for (int i = 0; i < 4; ++i) {
#pragma unroll
    for (int j = 0; j < 4; ++j) {
      int gn = n0 + wn * 64 + j * 16 + ccol;
      if (gn < nbound) {
        float bv = BIAS ? bias[gn] : 0.f;
        int gmb = m0 + wm * 64 + i * 16 + crow;
#pragma unroll
        for (int r = 0; r < 4; ++r) {
          float v = acc[i][j][r] + bv;
          if (OUT_BF16) ((unsigned short*)Cout)[(size_t)(gmb + r) * ldc + gn] = f2bf(v);
          else          ((float*)Cout)[(size_t)(gmb + r) * ldc + gn] = v;
        }
      }
    }
  }
}

__global__ __launch_bounds__(256) void gemm_bf16out_kernel(
    const unsigned short* __restrict__ A, const unsigned short* __restrict__ B,
    unsigned short* __restrict__ C, int K, int ldc) {
  gemm_body<true, false>(A, B, C, nullptr, K, ldc, 1 << 30, blockIdx.y * BM, blockIdx.x * BN);
}
__global__ __launch_bounds__(256) void gemm_f32bias_kernel(
    const unsigned short* __restrict__ A, const unsigned short* __restrict__ B,
    float* __restrict__ C, const float* __restrict__ bias, int K, int ldc, int nbound) {
  gemm_body<false, true>(A, B, C, bias, K, ldc, nbound, blockIdx.y * BM, blockIdx.x * BN);
}

// ---------------- setup kernels ----------------
__global__ __launch_bounds__(256) void cast_bf16_kernel(
    const float* __restrict__ src, unsigned short* __restrict__ dst, int n4) {
  int i = blockIdx.x * 256 + threadIdx.x;
  if (i < n4) {
    float4 v = ((const float4*)src)[i];
    ushort4 o;
    o.x = f2bf(v.x); o.y = f2bf(v.y); o.z = f2bf(v.z); o.w = f2bf(v.w);
    ((ushort4*)dst)[i] = o;
  }
}
__global__ __launch_bounds__(256) void cast_wihc_kernel(
    const float* __restrict__ wih, unsigned short* __restrict__ dst) {
  int i = blockIdx.x * 256 + threadIdx.x;           // 786432
  int j = i >> 9, c = i & 511;
  dst[i] = f2bf(wih[(size_t)j * 7137 + c]);
}
__global__ __launch_bounds__(256) void cast_genw_kernel(
    const float* __restrict__ g, unsigned short* __restrict__ dst) {
  int i = blockIdx.x * 256 + threadIdx.x;           // 3407872
  if (i < 6656 * 512) {
    int nrow = i >> 9, c = i & 511;
    float v = (nrow < 6625) ? g[(size_t)nrow * 512 + c] : 0.f;
    dst[i] = f2bf(v);
  }
}
__global__ __launch_bounds__(256) void transpose_oh_kernel(
    const float* __restrict__ wih, unsigned short* __restrict__ dst) {
  __shared__ float tile[32][33];
  int t0 = blockIdx.x * 32;
  int j0 = blockIdx.y * 32;
  int c = threadIdx.x & 31;
  int r4 = threadIdx.x >> 5;
#pragma unroll
  for (int rr = 0; rr < 4; ++rr) {
    int r = r4 + rr * 8;
    int tcol = t0 + c;
    tile[r][c] = (tcol < 6625) ? wih[(size_t)(j0 + r) * 7137 + 512 + tcol] : 0.f;
  }
  __syncthreads();
#pragma unroll
  for (int rr = 0; rr < 4; ++rr) {
    int r = r4 + rr * 8;
    int trow = t0 + r;
    if (trow < 6625) dst[(size_t)trow * 1536 + j0 + c] = f2bf(tile[c][r]);
  }
}
__global__ __launch_bounds__(256) void concat_bias_kernel(
    const float* __restrict__ h2h_b, const float* __restrict__ bhh, float* __restrict__ bias1) {
  int i = blockIdx.x * 256 + threadIdx.x;   // 2048
  bias1[i] = (i < 512) ? h2h_b[i] : bhh[i - 512];
}

// ---------------- grid barrier (two-level, monotonic counters) ----------------
__device__ __forceinline__ void gbar(unsigned* bar, int bid, unsigned it) {
  __syncthreads();
  if (threadIdx.x == 0) {
    __threadfence();                                 // agent-scope release
    unsigned* leaf = bar + (bid >> 5) * 32;          // 8 leaves, 128B apart
    unsigned* root = bar + 512;
    unsigned* gate = bar + 544;
    unsigned p = __hip_atomic_fetch_add(leaf, 1u, __ATOMIC_RELAXED, __HIP_MEMORY_SCOPE_AGENT);
    if (p == it * 32u - 1u) {
      unsigned q = __hip_atomic_fetch_add(root, 1u, __ATOMIC_RELAXED, __HIP_MEMORY_SCOPE_AGENT);
      if (q == it * 8u - 1u)
        __hip_atomic_store(gate, it, __ATOMIC_RELAXED, __HIP_MEMORY_SCOPE_AGENT);
    }
    while (__hip_atomic_load(gate, __ATOMIC_RELAXED, __HIP_MEMORY_SCOPE_AGENT) < it)
      __builtin_amdgcn_s_sleep(2);
    __threadfence();                                 // agent-scope acquire
  }
  __syncthreads();
}

// ---------------- persistent 25-step loop ----------------
// grid = 256 blocks x 256 threads, one block per CU (82KB dynamic LDS).
__global__ __launch_bounds__(256) void loop_kernel(
    const unsigned short* __restrict__ proj_bf,   // [20480, 512]
    const unsigned short* __restrict__ inputs_bf, // [20480, 512]
    const unsigned short* __restrict__ W1,        // [2048, 512]  = [h2h_w; whh]
    const float* __restrict__ bias1,              // [2048]       = [h2h_b; bhh]
    const unsigned short* __restrict__ wihc,      // [1536, 512]
    const float* __restrict__ score_w,            // [512]
    const unsigned short* __restrict__ ohT,       // [6625, 1536]
    const int* __restrict__ targets,              // [256, 25]
    const float* __restrict__ bih,                // [1536]
    float* __restrict__ ppgh,                     // [256, 2048]
    unsigned short* __restrict__ ctx_bf,          // [256, 512]
    unsigned short* __restrict__ h_bf,            // [256, 512]
    unsigned short* __restrict__ hid_bf,          // [6400, 512]
    unsigned* bar)
{
  extern __shared__ unsigned short smem[];
  unsigned short* ip_lds = smem;                  // 40960 bf16 = this block's inputs[b]
  float* e_s = (float*)(smem + 40960);            // 80
  float* alpha_s = e_s + 80;                      // 80

  const int bid = blockIdx.x;
  const int tid = threadIdx.x;
  const int lane = tid & 63;
  const int w = tid >> 6;

  // stage inputs[bid] into LDS once; persists across all 25 steps
  {
    const unsigned short* src = inputs_bf + (size_t)bid * 40960;
    for (int i = tid; i < 5120; i += 256)
      *(i32x4*)(ip_lds + i * 8) = *(const i32x4*)(src + i * 8);
  }
  float swv[8];
  *(float4*)&swv[0] = *(const float4*)(score_w + lane * 8);
  *(float4*)&swv[4] = *(const float4*)(score_w + lane * 8 + 4);
  __syncthreads();

  // P1: 256 blocks, 32x64 tiles over [256, 2048]
  const int p1_m0 = (bid >> 5) * 32;
  const int p1_n0 = (bid & 31) * 64;
  // P3: 64 blocks, 32 batch-rows x 64 j-cols (x 3 gates)
  const int p3_m0 = ((bid >> 3) & 7) * 32;
  const int p3_j0 = (bid & 7) * 64;

  unsigned it = 0;
  for (int s = 0; s < 25; ++s) {
    // ---- P1: ppgh = h @ W1^T + bias1 ----
    {
      const unsigned short* Ar = h_bf + (size_t)(p1_m0 + (lane & 15)) * 512 + (lane >> 4) * 8;
      const unsigned short* Br = W1 + (size_t)(p1_n0 + w * 16 + (lane & 15)) * 512 + (lane >> 4) * 8;
      f32x4 acc0 = 0.f, acc1 = 0.f;
#pragma unroll 4
      for (int kk = 0; kk < 16; ++kk) {
        i32x4 a0 = *(const i32x4*)(Ar + kk * 32);
        i32x4 a1 = *(const i32x4*)(Ar + 16 * 512 + kk * 32);
        i32x4 b  = *(const i32x4*)(Br + kk * 32);
        mfma_bf16_16x16x32(acc0, a0, b);
        mfma_bf16_16x16x32(acc1, a1, b);
      }
      const int col = p1_n0 + w * 16 + (lane & 15);
      const float bv = bias1[col];
      const int r0 = p1_m0 + (lane >> 4) * 4;
#pragma unroll
      for (int r = 0; r < 4; ++r) {
        ppgh[(size_t)(r0 + r) * 2048 + col] = acc0[r] + bv;
        ppgh[(size_t)(r0 + 16 + r) * 2048 + col] = acc1[r] + bv;
      }
    }
    ++it; gbar(bar, bid, it);

    // ---- P2: attention for batch `bid` ----
    {
      const int b = bid;
      float ppv[8];
      *(float4*)&ppv[0] = *(const float4*)(ppgh + (size_t)b * 2048 + lane * 8);
      *(float4*)&ppv[4] = *(const float4*)(ppgh + (size_t)b * 2048 + lane * 8 + 4);
      for (int t = w; t < 80; t += 4) {
        union { i32x4 v; unsigned short us[8]; } u;
        u.v = *(const i32x4*)(proj_bf + (size_t)(b * 80 + t) * 512 + lane * 8);
        float acc = 0.f;
#pragma unroll
        for (int j = 0; j < 8; ++j) acc += fast_tanh(bf2f(u.us[j]) + ppv[j]) * swv[j];
#pragma unroll
        for (int m = 32; m >= 1; m >>= 1) acc += __shfl_xor(acc, m, 64);
        if (lane == 0) e_s[t] = acc;
      }
      __syncthreads();
      if (w == 0) {
        float v0 = e_s[lane];
        float v1 = (lane < 16) ? e_s[64 + lane] : -1e30f;
        float mx = fmaxf(v0, v1);
#pragma unroll
        for (int m = 32; m >= 1; m >>= 1) mx = fmaxf(mx, __shfl_xor(mx, m, 64));
        float a0 = fast_exp(v0 - mx);
        float a1 = (lane < 16) ? fast_exp(v1 - mx) : 0.f;
        float sm = a0 + a1;
#pragma unroll
        for (int m = 32; m >= 1; m >>= 1) sm += __shfl_xor(sm, m, 64);
        float inv = frcp(sm);
        alpha_s[lane] = a0 * inv;
        if (lane < 16) alpha_s[64 + lane] = a1 * inv;
      }
      __syncthreads();
      float acc0 = 0.f, acc1 = 0.f;
#pragma unroll 8
      for (int t = 0; t < 80; ++t) {
        float al = alpha_s[t];
        acc0 += al * bf2f(ip_lds[t * 512 + tid]);
        acc1 += al * bf2f(ip_lds[t * 512 + 256 + tid]);
      }
      ctx_bf[b * 512 + tid] = f2bf(acc0);
      ctx_bf[b * 512 + 256 + tid] = f2bf(acc1);
    }
    ++it; gbar(bar, bid, it);

    // ---- P3: gi = ctx @ wihc^T (+bih +onehot row) fused with GRU cell ----
    if (bid < 64) {
      const int jcol = p3_j0 + w * 16 + (lane & 15);
      const unsigned short* Ar = ctx_bf + (size_t)(p3_m0 + (lane & 15)) * 512 + (lane >> 4) * 8;
      const unsigned short* B0 = wihc + (size_t)jcol * 512 + (lane >> 4) * 8;
      const unsigned short* B1 = wihc + (size_t)(512 + jcol) * 512 + (lane >> 4) * 8;
      const unsigned short* B2 = wihc + (size_t)(1024 + jcol) * 512 + (lane >> 4) * 8;
      f32x4 aR0 = 0.f, aR1 = 0.f, aZ0 = 0.f, aZ1 = 0.f, aN0 = 0.f, aN1 = 0.f;
#pragma unroll 4
      for (int kk = 0; kk < 16; ++kk) {
        i32x4 a0 = *(const i32x4*)(Ar + kk * 32);
        i32x4 a1 = *(const i32x4*)(Ar + 16 * 512 + kk * 32);
        i32x4 b0 = *(const i32x4*)(B0 + kk * 32);
        i32x4 b1 = *(const i32x4*)(B1 + kk * 32);
        i32x4 b2 = *(const i32x4*)(B2 + kk * 32);
        mfma_bf16_16x16x32(aR0, a0, b0); mfma_bf16_16x16x32(aR1, a1, b0);
        mfma_bf16_16x16x32(aZ0, a0, b1); mfma_bf16_16x16x32(aZ1, a1, b1);
        mfma_bf16_16x16x32(aN0, a0, b2); mfma_bf16_16x16x32(aN1, a1, b2);
      }
      const float bihr = bih[jcol], bihz = bih[512 + jcol], bihn = bih[1024 + jcol];
#pragma unroll
      for (int fi = 0; fi < 2; ++fi) {
        f32x4 vR = fi ? aR1 : aR0;
        f32x4 vZ = fi ? aZ1 : aZ0;
        f32x4 vN = fi ? aN1 : aN0;
#pragma unroll
        for (int r = 0; r < 4; ++r) {
          int b_ = p3_m0 + fi * 16 + (lane >> 4) * 4 + r;
          int tgt = targets[b_ * 25 + s];
          const unsigned short* oh = ohT + (size_t)tgt * 1536;
          float ir  = vR[r] + bihr + bf2f(oh[jcol]);
          float iz  = vZ[r] + bihz + bf2f(oh[512 + jcol]);
          float in_ = vN[r] + bihn + bf2f(oh[1024 + jcol]);
          const float* ghb = ppgh + (size_t)b_ * 2048 + 512;
          float rr = fast_sigmoid(ir + ghb[jcol]);
          float zz = fast_sigmoid(iz + ghb[512 + jcol]);
          float nn = fast_tanh(in_ + rr * ghb[1024 + jcol]);
          float h = (1.f - zz) * nn + zz * bf2f(h_bf[(size_t)b_ * 512 + jcol]);
          unsigned short hb = f2bf(h);
          h_bf[(size_t)b_ * 512 + jcol] = hb;
          hid_bf[(size_t)(b_ * 25 + s) * 512 + jcol] = hb;
        }
      }
    }
    ++it; gbar(bar, bid, it);
  }
}

extern "C" void kernel_launch(void* const* d_in, const int* in_sizes, int n_in,
                              void* d_out, int out_size, void* d_ws, size_t ws_size,
                              hipStream_t stream) {
  (void)in_sizes; (void)n_in; (void)out_size; (void)ws_size;
  const float* inputs  = (const float*)d_in[0];
  const int*   targets = (const int*)d_in[1];
  const float* i2h_w   = (const float*)d_in[3];
  const float* h2h_w   = (const float*)d_in[4];
  const float* h2h_b   = (const float*)d_in[5];
  const float* score_w = (const float*)d_in[6];
  const float* gru_wih = (const float*)d_in[7];
  const float* gru_whh = (const float*)d_in[8];
  const float* gru_bih = (const float*)d_in[9];
  const float* gru_bhh = (const float*)d_in[10];
  const float* gen_w   = (const float*)d_in[11];
  const float* gen_b   = (const float*)d_in[12];
  float* out = (float*)d_out;

  char* ws = (char*)d_ws;
  size_t off = 0;
  auto alloc = [&](size_t bytes) {
    char* p = ws + off;
    off += (bytes + 255) & ~(size_t)255;
    return p;
  };
  unsigned short* inputs_bf = (unsigned short*)alloc(10485760ull * 2);
  unsigned short* proj_bf   = (unsigned short*)alloc(10485760ull * 2);
  unsigned short* i2h_bf    = (unsigned short*)alloc(262144ull * 2);
  unsigned short* W1_bf     = (unsigned short*)alloc(1048576ull * 2);  // [2048,512]
  unsigned short* wihc_bf   = (unsigned short*)alloc(786432ull * 2);
  unsigned short* ohT_bf    = (unsigned short*)alloc(10176000ull * 2);
  unsigned short* genw_bf   = (unsigned short*)alloc(3407872ull * 2);
  float*          ppgh      = (float*)alloc(524288ull * 4);
  float*          bias1     = (float*)alloc(2048ull * 4);
  unsigned short* ctx_bf    = (unsigned short*)alloc(131072ull * 2);
  unsigned short* h_bf      = (unsigned short*)alloc(131072ull * 2);
  unsigned short* hid_bf    = (unsigned short*)alloc(3276800ull * 2);
  unsigned*       bar       = (unsigned*)alloc(1024ull * 4);

  // prologue
  cast_bf16_kernel<<<10240, 256, 0, stream>>>(inputs, inputs_bf, 2621440);
  cast_bf16_kernel<<<256, 256, 0, stream>>>(i2h_w, i2h_bf, 65536);
  cast_bf16_kernel<<<256, 256, 0, stream>>>(h2h_w, W1_bf, 65536);
  cast_bf16_kernel<<<768, 256, 0, stream>>>(gru_whh, W1_bf + 262144, 196608);
  cast_wihc_kernel<<<3072, 256, 0, stream>>>(gru_wih, wihc_bf);
  transpose_oh_kernel<<<dim3(208, 48), 256, 0, stream>>>(gru_wih, ohT_bf);
  cast_genw_kernel<<<13312, 256, 0, stream>>>(gen_w, genw_bf);
  concat_bias_kernel<<<8, 256, 0, stream>>>(h2h_b, gru_bhh, bias1);
  gemm_bf16out_kernel<<<dim3(4, 160), 256, 0, stream>>>(inputs_bf, i2h_bf, proj_bf, 512, 512);
  hipMemsetAsync(h_bf, 0, 131072 * 2, stream);
  hipMemsetAsync(bar, 0, 4096, stream);

  // persistent 25-step loop (cooperative: guarantees 256-block co-residency)
  {
    void* args[] = {
      (void*)&proj_bf, (void*)&inputs_bf, (void*)&W1_bf, (void*)&bias1,
      (void*)&wihc_bf, (void*)&score_w, (void*)&ohT_bf, (void*)&targets,
      (void*)&gru_bih, (void*)&ppgh, (void*)&ctx_bf, (void*)&h_bf,
      (void*)&hid_bf, (void*)&bar
    };
    hipLaunchCooperativeKernel(reinterpret_cast<void*>(loop_kernel),
                               dim3(256), dim3(256), args, 82560, stream);
  }

  // epilogue: probs = hiddens @ gen_w.T + gen_b
  gemm_f32bias_kernel<<<dim3(52, 50), 256, 0, stream>>>(hid_bf, genw_bf, out, gen_b, 512, 6625, 6625);
}

// Round 3
// 1387.798 us; speedup vs baseline: 1.5015x; 1.5015x over previous
//
#include <hip/hip_runtime.h>
#include <stdint.h>

typedef float f32x4 __attribute__((ext_vector_type(4)));
typedef int i32x4 __attribute__((ext_vector_type(4)));

#define LOG2E 1.4426950408889634f

__device__ __forceinline__ float bf2f(unsigned short u) {
  union { unsigned int i; float f; } x; x.i = ((unsigned int)u) << 16; return x.f;
}
__device__ __forceinline__ unsigned short f2bf(float f) {
  union { float f; unsigned int i; } x; x.f = f;
  unsigned int u = x.i + 0x7fffu + ((x.i >> 16) & 1u);
  return (unsigned short)(u >> 16);
}
__device__ __forceinline__ float fexp2(float x) {
#if __has_builtin(__builtin_amdgcn_exp2f)
  return __builtin_amdgcn_exp2f(x);
#else
  return exp2f(x);
#endif
}
__device__ __forceinline__ float frcp(float x) {
#if __has_builtin(__builtin_amdgcn_rcpf)
  return __builtin_amdgcn_rcpf(x);
#else
  return 1.f / x;
#endif
}
__device__ __forceinline__ float fast_exp(float x) { return fexp2(x * LOG2E); }
__device__ __forceinline__ float fast_tanh(float x) {
  float e = fexp2(x * (2.f * LOG2E));
  return 1.f - 2.f * frcp(e + 1.f);
}
__device__ __forceinline__ float fast_sigmoid(float x) {
  return frcp(1.f + fexp2(-x * LOG2E));
}

__device__ __forceinline__ void mfma_bf16_16x16x32(f32x4& d, i32x4 a, i32x4 b) {
  asm("v_mfma_f32_16x16x32_bf16 %0, %1, %2, %0" : "+v"(d) : "v"(a), "v"(b));
}

__device__ __forceinline__ void stage16(const unsigned short* g, unsigned short* lds_wave_base, int lane) {
#if __has_builtin(__builtin_amdgcn_global_load_lds)
  __builtin_amdgcn_global_load_lds(
      (const __attribute__((address_space(1))) unsigned int*)(uintptr_t)g,
      (__attribute__((address_space(3))) unsigned int*)(uintptr_t)lds_wave_base,
      16, 0, 0);
#else
  i32x4 v = *(const i32x4*)g;
  *(i32x4*)(lds_wave_base + lane * 8) = v;
#endif
}

// ---- device-coherent (LLC) access helpers: bypass per-XCD L2, no fences needed ----
__device__ __forceinline__ void st_f32_dc(float* p, float v) {
  __hip_atomic_store(p, v, __ATOMIC_RELAXED, __HIP_MEMORY_SCOPE_AGENT);
}
__device__ __forceinline__ float ld_f32_dc(const float* p) {
  return __hip_atomic_load((float*)p, __ATOMIC_RELAXED, __HIP_MEMORY_SCOPE_AGENT);
}
__device__ __forceinline__ void st_u64_dc(void* p, unsigned long long v) {
  __hip_atomic_store((unsigned long long*)p, v, __ATOMIC_RELAXED, __HIP_MEMORY_SCOPE_AGENT);
}
__device__ __forceinline__ unsigned long long ld_u64_dc(const void* p) {
  return __hip_atomic_load((unsigned long long*)p, __ATOMIC_RELAXED, __HIP_MEMORY_SCOPE_AGENT);
}
// 16B MFMA fragment (8 bf16) from an LLC-coherent buffer, as 2x8B atomic loads
__device__ __forceinline__ i32x4 ld_frag_dc(const unsigned short* p) {
  union { unsigned long long q[2]; i32x4 v; } u;
  u.q[0] = ld_u64_dc(p);
  u.q[1] = ld_u64_dc(p + 4);
  return u.v;
}

// ---------------- LDS-staged GEMM (prologue proj + final probs) ----------------
#define BM 128
#define BN 128
#define BK 32

template <bool OUT_BF16, bool BIAS>
__device__ __forceinline__ void gemm_body(
    const unsigned short* __restrict__ A, const unsigned short* __restrict__ B,
    void* __restrict__ Cout, const float* __restrict__ bias,
    int K, int ldc, int nbound, int m0, int n0)
{
  __shared__ __align__(16) unsigned short lA[BM * BK];
  __shared__ __align__(16) unsigned short lB[BN * BK];
  const int tid = threadIdx.x;
  const int lane = tid & 63;
  const int w = tid >> 6;
  const int wm = w >> 1, wn = w & 1;
  const int frag_row = lane & 15;
  const int kgrp = lane >> 4;

  f32x4 acc[4][4];
#pragma unroll
  for (int i = 0; i < 4; ++i)
#pragma unroll
    for (int j = 0; j < 4; ++j) acc[i][j] = 0.f;

  const int nK = K / BK;
  const int c0 = tid, c1 = tid + 256;
  for (int kt = 0; kt < nK; ++kt) {
    const int kb = kt * BK;
    stage16(A + (size_t)(m0 + (c0 >> 2)) * K + kb + (c0 & 3) * 8, lA + (w * 64) * 8, lane);
    stage16(A + (size_t)(m0 + (c1 >> 2)) * K + kb + (c1 & 3) * 8, lA + (256 + w * 64) * 8, lane);
    stage16(B + (size_t)(n0 + (c0 >> 2)) * K + kb + (c0 & 3) * 8, lB + (w * 64) * 8, lane);
    stage16(B + (size_t)(n0 + (c1 >> 2)) * K + kb + (c1 & 3) * 8, lB + (256 + w * 64) * 8, lane);
    __syncthreads();

    i32x4 af[4], bfr[4];
#pragma unroll
    for (int i = 0; i < 4; ++i) {
      int ra = wm * 64 + i * 16 + frag_row;
      af[i] = *(const i32x4*)&lA[ra * BK + kgrp * 8];
      int rb = wn * 64 + i * 16 + frag_row;
      bfr[i] = *(const i32x4*)&lB[rb * BK + kgrp * 8];
    }
#pragma unroll
    for (int i = 0; i < 4; ++i)
#pragma unroll
      for (int j = 0; j < 4; ++j) mfma_bf16_16x16x32(acc[i][j], af[i], bfr[j]);
    __syncthreads();
  }

  const int crow = (lane >> 4) * 4;
  const int ccol = lane & 15;
#pragma unroll
  for (int i = 0; i < 4; ++i) {
#pragma unroll
    for (int j = 0; j < 4; ++j) {
      int gn = n0 + wn * 64 + j * 16 + ccol;
      if (gn < nbound) {
        float bv = BIAS ? bias[gn] : 0.f;
        int gmb = m0 + wm * 64 + i * 16 + crow;
#pragma unroll
        for (int r = 0; r < 4; ++r) {
          float v = acc[i][j][r] + bv;
          if (OUT_BF16) ((unsigned short*)Cout)[(size_t)(gmb + r) * ldc + gn] = f2bf(v);
          else          ((float*)Cout)[(size_t)(gmb + r) * ldc + gn] = v;
        }
      }
    }
  }
}

__global__ __launch_bounds__(256) void gemm_bf16out_kernel(
    const unsigned short* __restrict__ A, const unsigned short* __restrict__ B,
    unsigned short* __restrict__ C, int K, int ldc) {
  gemm_body<true, false>(A, B, C, nullptr, K, ldc, 1 << 30, blockIdx.y * BM, blockIdx.x * BN);
}
__global__ __launch_bounds__(256) void gemm_f32bias_kernel(
    const unsigned short* __restrict__ A, const unsigned short* __restrict__ B,
    float* __restrict__ C, const float* __restrict__ bias, int K, int ldc, int nbound) {
  gemm_body<false, true>(A, B, C, bias, K, ldc, nbound, blockIdx.y * BM, blockIdx.x * BN);
}

// ---------------- setup kernels ----------------
__global__ __launch_bounds__(256) void cast_bf16_kernel(
    const float* __restrict__ src, unsigned short* __restrict__ dst, int n4) {
  int i = blockIdx.x * 256 + threadIdx.x;
  if (i < n4) {
    float4 v = ((const float4*)src)[i];
    ushort4 o;
    o.x = f2bf(v.x); o.y = f2bf(v.y); o.z = f2bf(v.z); o.w = f2bf(v.w);
    ((ushort4*)dst)[i] = o;
  }
}
__global__ __launch_bounds__(256) void cast_wihc_kernel(
    const float* __restrict__ wih, unsigned short* __restrict__ dst) {
  int i = blockIdx.x * 256 + threadIdx.x;           // 786432
  int j = i >> 9, c = i & 511;
  dst[i] = f2bf(wih[(size_t)j * 7137 + c]);
}
__global__ __launch_bounds__(256) void cast_genw_kernel(
    const float* __restrict__ g, unsigned short* __restrict__ dst) {
  int i = blockIdx.x * 256 + threadIdx.x;           // 3407872
  if (i < 6656 * 512) {
    int nrow = i >> 9, c = i & 511;
    float v = (nrow < 6625) ? g[(size_t)nrow * 512 + c] : 0.f;
    dst[i] = f2bf(v);
  }
}
__global__ __launch_bounds__(256) void transpose_oh_kernel(
    const float* __restrict__ wih, unsigned short* __restrict__ dst) {
  __shared__ float tile[32][33];
  int t0 = blockIdx.x * 32;
  int j0 = blockIdx.y * 32;
  int c = threadIdx.x & 31;
  int r4 = threadIdx.x >> 5;
#pragma unroll
  for (int rr = 0; rr < 4; ++rr) {
    int r = r4 + rr * 8;
    int tcol = t0 + c;
    tile[r][c] = (tcol < 6625) ? wih[(size_t)(j0 + r) * 7137 + 512 + tcol] : 0.f;
  }
  __syncthreads();
#pragma unroll
  for (int rr = 0; rr < 4; ++rr) {
    int r = r4 + rr * 8;
    int trow = t0 + r;
    if (trow < 6625) dst[(size_t)trow * 1536 + j0 + c] = f2bf(tile[c][r]);
  }
}
__global__ __launch_bounds__(256) void concat_bias_kernel(
    const float* __restrict__ h2h_b, const float* __restrict__ bhh, float* __restrict__ bias1) {
  int i = blockIdx.x * 256 + threadIdx.x;   // 2048
  bias1[i] = (i < 512) ? h2h_b[i] : bhh[i - 512];
}

// ---------------- fence-free grid barrier (LLC atomics only, no L2 flush) ----------------
__device__ __forceinline__ void gbar(unsigned* bar, int bid, unsigned it) {
  // drain own vmem (incl. agent-scope stores) before signaling
  asm volatile("s_waitcnt vmcnt(0) lgkmcnt(0)" ::: "memory");
  __syncthreads();
  if (threadIdx.x == 0) {
    unsigned* leaf = bar + (bid >> 5) * 32;          // 8 leaves, 128B apart
    unsigned* root = bar + 512;
    unsigned* gate = bar + 544;
    unsigned p = __hip_atomic_fetch_add(leaf, 1u, __ATOMIC_RELAXED, __HIP_MEMORY_SCOPE_AGENT);
    if (p == it * 32u - 1u) {
      unsigned q = __hip_atomic_fetch_add(root, 1u, __ATOMIC_RELAXED, __HIP_MEMORY_SCOPE_AGENT);
      if (q == it * 8u - 1u)
        __hip_atomic_store(gate, it, __ATOMIC_RELAXED, __HIP_MEMORY_SCOPE_AGENT);
    }
    while (__hip_atomic_load(gate, __ATOMIC_RELAXED, __HIP_MEMORY_SCOPE_AGENT) < it)
      __builtin_amdgcn_s_sleep(1);
  }
  __syncthreads();
}

// ---------------- persistent 25-step loop ----------------
// grid = 256 blocks x 512 threads (8 waves/CU), ~86.6KB dynamic LDS -> 1 block/CU.
// Cross-block data (ppgh, ctx_bf, h_bf) ONLY via LLC-coherent atomics; weights/proj/
// inputs/ohT via normal cached loads (L2 stays warm across steps: no fences).
__global__ __launch_bounds__(512) void loop_kernel(
    const unsigned short* __restrict__ proj_bf,   // [20480, 512]
    const unsigned short* __restrict__ inputs_bf, // [20480, 512]
    const unsigned short* __restrict__ W1,        // [2048, 512]  = [h2h_w; whh]
    const float* __restrict__ bias1,              // [2048]       = [h2h_b; bhh]
    const unsigned short* __restrict__ wihc,      // [1536, 512]
    const float* __restrict__ score_w,            // [512]
    const unsigned short* __restrict__ ohT,       // [6625, 1536]
    const int* __restrict__ targets,              // [256, 25]
    const float* __restrict__ bih,                // [1536]
    float* __restrict__ ppgh,                     // [256, 2048]
    unsigned short* __restrict__ ctx_bf,          // [256, 512]
    unsigned short* __restrict__ h_bf,            // [256, 512]
    unsigned short* __restrict__ hid_bf,          // [6400, 512]
    unsigned* bar)
{
  extern __shared__ char smem[];
  unsigned short* ip_lds = (unsigned short*)smem;            // 81920 B
  float* e_s       = (float*)(smem + 81920);                 // 320 B
  float* alpha_s   = (float*)(smem + 82240);                 // 320 B
  float* ctx_stage = (float*)(smem + 82560);                 // 2048 B
  unsigned short* h_stage = (unsigned short*)(smem + 84608); // 4096 B

  const int bid = blockIdx.x;
  const int tid = threadIdx.x;
  const int lane = tid & 63;
  const int w = tid >> 6;
  const int wm = w >> 2, wn = w & 3;
  const int fr = lane & 15, kg = lane >> 4;

  // stage this block's inputs[b] into LDS once (persists across steps)
  {
    const unsigned short* isrc = inputs_bf + (size_t)bid * 40960;
    for (int i = tid; i < 5120; i += 512)
      *(i32x4*)(ip_lds + i * 8) = *(const i32x4*)(isrc + i * 8);
  }
  float swv[8];
  *(float4*)&swv[0] = *(const float4*)(score_w + lane * 8);
  *(float4*)&swv[4] = *(const float4*)(score_w + lane * 8 + 4);
  __syncthreads();

  const int p1_m0 = (bid >> 5) * 32, p1_n0 = (bid & 31) * 64;
  const int p3_m0 = (bid >> 3) * 32, p3_j0 = (bid & 7) * 64;   // used when bid<64
  float hold[4] = {0.f, 0.f, 0.f, 0.f};                        // register-carried h_old

  unsigned it = 0;
  for (int s = 0; s < 25; ++s) {
    // ---- P1: ppgh = h @ W1^T + bias1  (wave tile 16x16, K=512) ----
    {
      const unsigned short* Ar = h_bf + (size_t)(p1_m0 + wm * 16 + fr) * 512 + kg * 8;
      const unsigned short* Br = W1 + (size_t)(p1_n0 + wn * 16 + fr) * 512 + kg * 8;
      f32x4 acc = 0.f;
#pragma unroll 4
      for (int kk = 0; kk < 16; ++kk) {
        i32x4 a = ld_frag_dc(Ar + kk * 32);
        i32x4 b = *(const i32x4*)(Br + kk * 32);
        mfma_bf16_16x16x32(acc, a, b);
      }
      const int col = p1_n0 + wn * 16 + fr;
      const float bv = bias1[col];
      const int r0 = p1_m0 + wm * 16 + kg * 4;
#pragma unroll
      for (int r = 0; r < 4; ++r)
        st_f32_dc(&ppgh[(size_t)(r0 + r) * 2048 + col], acc[r] + bv);
    }
    ++it; gbar(bar, bid, it);

    // ---- P2: attention for batch `bid` ----
    {
      const int b = bid;
      float ppv[8];
#pragma unroll
      for (int j = 0; j < 8; ++j)
        ppv[j] = ld_f32_dc(&ppgh[(size_t)b * 2048 + lane * 8 + j]);
      for (int t = w; t < 80; t += 8) {
        union { i32x4 v; unsigned short us[8]; } u;
        u.v = *(const i32x4*)(proj_bf + (size_t)(b * 80 + t) * 512 + lane * 8);
        float acc = 0.f;
#pragma unroll
        for (int j = 0; j < 8; ++j) acc += fast_tanh(bf2f(u.us[j]) + ppv[j]) * swv[j];
#pragma unroll
        for (int m = 32; m >= 1; m >>= 1) acc += __shfl_xor(acc, m, 64);
        if (lane == 0) e_s[t] = acc;
      }
      __syncthreads();
      if (w == 0) {
        float v0 = e_s[lane];
        float v1 = (lane < 16) ? e_s[64 + lane] : -1e30f;
        float mx = fmaxf(v0, v1);
#pragma unroll
        for (int m = 32; m >= 1; m >>= 1) mx = fmaxf(mx, __shfl_xor(mx, m, 64));
        float a0 = fast_exp(v0 - mx);
        float a1 = (lane < 16) ? fast_exp(v1 - mx) : 0.f;
        float sm = a0 + a1;
#pragma unroll
        for (int m = 32; m >= 1; m >>= 1) sm += __shfl_xor(sm, m, 64);
        float inv = frcp(sm);
        alpha_s[lane] = a0 * inv;
        if (lane < 16) alpha_s[64 + lane] = a1 * inv;
      }
      __syncthreads();
      float acc = 0.f;
#pragma unroll 8
      for (int t = 0; t < 80; ++t) acc += alpha_s[t] * bf2f(ip_lds[t * 512 + tid]);
      ctx_stage[tid] = acc;
      __syncthreads();
      if (tid < 128) {
        union { unsigned short us[4]; unsigned long long q; } u;
#pragma unroll
        for (int j = 0; j < 4; ++j) u.us[j] = f2bf(ctx_stage[tid * 4 + j]);
        st_u64_dc(&ctx_bf[(size_t)b * 512 + tid * 4], u.q);
      }
    }
    ++it; gbar(bar, bid, it);

    // ---- P3: gi = ctx @ wihc^T fused with GRU cell (blocks 0..63) ----
    if (bid < 64) {
      const int jcol = p3_j0 + wn * 16 + fr;
      const unsigned short* Ar = ctx_bf + (size_t)(p3_m0 + wm * 16 + fr) * 512 + kg * 8;
      const unsigned short* B0 = wihc + (size_t)jcol * 512 + kg * 8;
      const unsigned short* B1 = B0 + 512 * 512;
      const unsigned short* B2 = B1 + 512 * 512;
      f32x4 aR = 0.f, aZ = 0.f, aN = 0.f;
#pragma unroll 4
      for (int kk = 0; kk < 16; ++kk) {
        i32x4 a = ld_frag_dc(Ar + kk * 32);
        mfma_bf16_16x16x32(aR, a, *(const i32x4*)(B0 + kk * 32));
        mfma_bf16_16x16x32(aZ, a, *(const i32x4*)(B1 + kk * 32));
        mfma_bf16_16x16x32(aN, a, *(const i32x4*)(B2 + kk * 32));
      }
      const float bihr = bih[jcol], bihz = bih[512 + jcol], bihn = bih[1024 + jcol];
      const int r0 = p3_m0 + wm * 16 + kg * 4;
#pragma unroll
      for (int r = 0; r < 4; ++r) {
        const int b_ = r0 + r;
        const int tgt = targets[b_ * 25 + s];
        const unsigned short* oh = ohT + (size_t)tgt * 1536;
        const float* gb = ppgh + (size_t)b_ * 2048 + 512;
        float ir  = aR[r] + bihr + bf2f(oh[jcol])        + ld_f32_dc(&gb[jcol]);
        float iz  = aZ[r] + bihz + bf2f(oh[512 + jcol])  + ld_f32_dc(&gb[512 + jcol]);
        float in_ = aN[r] + bihn + bf2f(oh[1024 + jcol]);
        float hn  = ld_f32_dc(&gb[1024 + jcol]);
        float rr = fast_sigmoid(ir);
        float zz = fast_sigmoid(iz);
        float nn = fast_tanh(in_ + rr * hn);
        float h = (1.f - zz) * nn + zz * hold[r];
        hold[r] = h;
        unsigned short hb = f2bf(h);
        h_stage[(wm * 16 + kg * 4 + r) * 64 + wn * 16 + fr] = hb;
        hid_bf[(size_t)(b_ * 25 + s) * 512 + jcol] = hb;   // normal store (read after kernel end)
      }
    }
    __syncthreads();
    if (bid < 64) {
      // republish h row-major for P1's fragments (8B LLC stores)
      int m = tid >> 4, c = tid & 15;
      unsigned long long q = *(unsigned long long*)(h_stage + m * 64 + c * 4);
      st_u64_dc(&h_bf[(size_t)(p3_m0 + m) * 512 + p3_j0 + c * 4], q);
    }
    ++it; gbar(bar, bid, it);
  }
}

extern "C" void kernel_launch(void* const* d_in, const int* in_sizes, int n_in,
                              void* d_out, int out_size, void* d_ws, size_t ws_size,
                              hipStream_t stream) {
  (void)in_sizes; (void)n_in; (void)out_size; (void)ws_size;
  const float* inputs  = (const float*)d_in[0];
  const int*   targets = (const int*)d_in[1];
  const float* i2h_w   = (const float*)d_in[3];
  const float* h2h_w   = (const float*)d_in[4];
  const float* h2h_b   = (const float*)d_in[5];
  const float* score_w = (const float*)d_in[6];
  const float* gru_wih = (const float*)d_in[7];
  const float* gru_whh = (const float*)d_in[8];
  const float* gru_bih = (const float*)d_in[9];
  const float* gru_bhh = (const float*)d_in[10];
  const float* gen_w   = (const float*)d_in[11];
  const float* gen_b   = (const float*)d_in[12];
  float* out = (float*)d_out;

  char* ws = (char*)d_ws;
  size_t off = 0;
  auto alloc = [&](size_t bytes) {
    char* p = ws + off;
    off += (bytes + 255) & ~(size_t)255;
    return p;
  };
  unsigned short* inputs_bf = (unsigned short*)alloc(10485760ull * 2);
  unsigned short* proj_bf   = (unsigned short*)alloc(10485760ull * 2);
  unsigned short* i2h_bf    = (unsigned short*)alloc(262144ull * 2);
  unsigned short* W1_bf     = (unsigned short*)alloc(1048576ull * 2);  // [2048,512]
  unsigned short* wihc_bf   = (unsigned short*)alloc(786432ull * 2);
  unsigned short* ohT_bf    = (unsigned short*)alloc(10176000ull * 2);
  unsigned short* genw_bf   = (unsigned short*)alloc(3407872ull * 2);
  float*          ppgh      = (float*)alloc(524288ull * 4);
  float*          bias1     = (float*)alloc(2048ull * 4);
  unsigned short* ctx_bf    = (unsigned short*)alloc(131072ull * 2);
  unsigned short* h_bf      = (unsigned short*)alloc(131072ull * 2);
  unsigned short* hid_bf    = (unsigned short*)alloc(3276800ull * 2);
  unsigned*       bar       = (unsigned*)alloc(1024ull * 4);

  // prologue
  cast_bf16_kernel<<<10240, 256, 0, stream>>>(inputs, inputs_bf, 2621440);
  cast_bf16_kernel<<<256, 256, 0, stream>>>(i2h_w, i2h_bf, 65536);
  cast_bf16_kernel<<<256, 256, 0, stream>>>(h2h_w, W1_bf, 65536);
  cast_bf16_kernel<<<768, 256, 0, stream>>>(gru_whh, W1_bf + 262144, 196608);
  cast_wihc_kernel<<<3072, 256, 0, stream>>>(gru_wih, wihc_bf);
  transpose_oh_kernel<<<dim3(208, 48), 256, 0, stream>>>(gru_wih, ohT_bf);
  cast_genw_kernel<<<13312, 256, 0, stream>>>(gen_w, genw_bf);
  concat_bias_kernel<<<8, 256, 0, stream>>>(h2h_b, gru_bhh, bias1);
  gemm_bf16out_kernel<<<dim3(4, 160), 256, 0, stream>>>(inputs_bf, i2h_bf, proj_bf, 512, 512);
  hipMemsetAsync(h_bf, 0, 131072 * 2, stream);
  hipMemsetAsync(bar, 0, 4096, stream);

  // persistent 25-step loop (cooperative: guarantees co-residency)
  {
    void* args[] = {
      (void*)&proj_bf, (void*)&inputs_bf, (void*)&W1_bf, (void*)&bias1,
      (void*)&wihc_bf, (void*)&score_w, (void*)&ohT_bf, (void*)&targets,
      (void*)&gru_bih, (void*)&ppgh, (void*)&ctx_bf, (void*)&h_bf,
      (void*)&hid_bf, (void*)&bar
    };
    hipLaunchCooperativeKernel(reinterpret_cast<void*>(loop_kernel),
                               dim3(256), dim3(512), args, 88704, stream);
  }

  // epilogue: probs = hiddens @ gen_w.T + gen_b
  gemm_f32bias_kernel<<<dim3(52, 50), 256, 0, stream>>>(hid_bf, genw_bf, out, gen_b, 512, 6625, 6625);
}

// Round 7
// 1148.335 us; speedup vs baseline: 1.8146x; 1.2085x over previous
//
#include <hip/hip_runtime.h>
#include <stdint.h>

typedef float f32x4 __attribute__((ext_vector_type(4)));
typedef int i32x4 __attribute__((ext_vector_type(4)));

#define LOG2E 1.4426950408889634f

__device__ __forceinline__ float bf2f(unsigned short u) {
  union { unsigned int i; float f; } x; x.i = ((unsigned int)u) << 16; return x.f;
}
__device__ __forceinline__ unsigned short f2bf(float f) {
  union { float f; unsigned int i; } x; x.f = f;
  unsigned int u = x.i + 0x7fffu + ((x.i >> 16) & 1u);
  return (unsigned short)(u >> 16);
}
__device__ __forceinline__ float fexp2(float x) {
#if __has_builtin(__builtin_amdgcn_exp2f)
  return __builtin_amdgcn_exp2f(x);
#else
  return exp2f(x);
#endif
}
__device__ __forceinline__ float frcp(float x) {
#if __has_builtin(__builtin_amdgcn_rcpf)
  return __builtin_amdgcn_rcpf(x);
#else
  return 1.f / x;
#endif
}
__device__ __forceinline__ float fast_exp(float x) { return fexp2(x * LOG2E); }
__device__ __forceinline__ float fast_tanh(float x) {
  float e = fexp2(x * (2.f * LOG2E));
  return 1.f - 2.f * frcp(e + 1.f);
}
__device__ __forceinline__ float fast_sigmoid(float x) {
  return frcp(1.f + fexp2(-x * LOG2E));
}

__device__ __forceinline__ void mfma_bf16_16x16x32(f32x4& d, i32x4 a, i32x4 b) {
  asm("v_mfma_f32_16x16x32_bf16 %0, %1, %2, %0" : "+v"(d) : "v"(a), "v"(b));
}

__device__ __forceinline__ void stage16(const unsigned short* g, unsigned short* lds_wave_base, int lane) {
#if __has_builtin(__builtin_amdgcn_global_load_lds)
  __builtin_amdgcn_global_load_lds(
      (const __attribute__((address_space(1))) unsigned int*)(uintptr_t)g,
      (__attribute__((address_space(3))) unsigned int*)(uintptr_t)lds_wave_base,
      16, 0, 0);
#else
  i32x4 v = *(const i32x4*)g;
  *(i32x4*)(lds_wave_base + lane * 8) = v;
#endif
}

// ---------------- LDS-staged GEMM (prologue proj + final probs) — R1-proven ----------------
#define BM 128
#define BN 128
#define BK 32

template <bool OUT_BF16, bool BIAS>
__device__ __forceinline__ void gemm_body(
    const unsigned short* __restrict__ A, const unsigned short* __restrict__ B,
    void* __restrict__ Cout, const float* __restrict__ bias,
    int K, int ldc, int nbound, int m0, int n0)
{
  __shared__ __align__(16) unsigned short lA[BM * BK];
  __shared__ __align__(16) unsigned short lB[BN * BK];
  const int tid = threadIdx.x;
  const int lane = tid & 63;
  const int w = tid >> 6;
  const int wm = w >> 1, wn = w & 1;
  const int frag_row = lane & 15;
  const int kgrp = lane >> 4;

  f32x4 acc[4][4];
#pragma unroll
  for (int i = 0; i < 4; ++i)
#pragma unroll
    for (int j = 0; j < 4; ++j) acc[i][j] = 0.f;

  const int nK = K / BK;
  const int c0 = tid, c1 = tid + 256;
  for (int kt = 0; kt < nK; ++kt) {
    const int kb = kt * BK;
    stage16(A + (size_t)(m0 + (c0 >> 2)) * K + kb + (c0 & 3) * 8, lA + (w * 64) * 8, lane);
    stage16(A + (size_t)(m0 + (c1 >> 2)) * K + kb + (c1 & 3) * 8, lA + (256 + w * 64) * 8, lane);
    stage16(B + (size_t)(n0 + (c0 >> 2)) * K + kb + (c0 & 3) * 8, lB + (w * 64) * 8, lane);
    stage16(B + (size_t)(n0 + (c1 >> 2)) * K + kb + (c1 & 3) * 8, lB + (256 + w * 64) * 8, lane);
    __syncthreads();

    i32x4 af[4], bfr[4];
#pragma unroll
    for (int i = 0; i < 4; ++i) {
      int ra = wm * 64 + i * 16 + frag_row;
      af[i] = *(const i32x4*)&lA[ra * BK + kgrp * 8];
      int rb = wn * 64 + i * 16 + frag_row;
      bfr[i] = *(const i32x4*)&lB[rb * BK + kgrp * 8];
    }
#pragma unroll
    for (int i = 0; i < 4; ++i)
#pragma unroll
      for (int j = 0; j < 4; ++j) mfma_bf16_16x16x32(acc[i][j], af[i], bfr[j]);
    __syncthreads();
  }

  const int crow = (lane >> 4) * 4;
  const int ccol = lane & 15;
#pragma unroll
  for (int i = 0; i < 4; ++i) {
#pragma unroll
    for (int j = 0; j < 4; ++j) {
      int gn = n0 + wn * 64 + j * 16 + ccol;
      if (gn < nbound) {
        float bv = BIAS ? bias[gn] : 0.f;
        int gmb = m0 + wm * 64 + i * 16 + crow;
#pragma unroll
        for (int r = 0; r < 4; ++r) {
          float v = acc[i][j][r] + bv;
          if (OUT_BF16) ((unsigned short*)Cout)[(size_t)(gmb + r) * ldc + gn] = f2bf(v);
          else          ((float*)Cout)[(size_t)(gmb + r) * ldc + gn] = v;
        }
      }
    }
  }
}

__global__ __launch_bounds__(256) void gemm_bf16out_kernel(
    const unsigned short* __restrict__ A, const unsigned short* __restrict__ B,
    unsigned short* __restrict__ C, int K, int ldc) {
  gemm_body<true, false>(A, B, C, nullptr, K, ldc, 1 << 30, blockIdx.y * BM, blockIdx.x * BN);
}
__global__ __launch_bounds__(256) void gemm_f32bias_kernel(
    const unsigned short* __restrict__ A, const unsigned short* __restrict__ B,
    float* __restrict__ C, const float* __restrict__ bias, int K, int ldc, int nbound) {
  gemm_body<false, true>(A, B, C, bias, K, ldc, nbound, blockIdx.y * BM, blockIdx.x * BN);
}

// ---------------- setup kernels (all R1-proven) ----------------
__global__ __launch_bounds__(256) void cast_bf16_kernel(
    const float* __restrict__ src, unsigned short* __restrict__ dst, int n4) {
  int i = blockIdx.x * 256 + threadIdx.x;
  if (i < n4) {
    float4 v = ((const float4*)src)[i];
    ushort4 o;
    o.x = f2bf(v.x); o.y = f2bf(v.y); o.z = f2bf(v.z); o.w = f2bf(v.w);
    ((ushort4*)dst)[i] = o;
  }
}
__global__ __launch_bounds__(256) void cast_wihc_kernel(
    const float* __restrict__ wih, unsigned short* __restrict__ dst) {
  int i = blockIdx.x * 256 + threadIdx.x;           // 786432
  int j = i >> 9, c = i & 511;
  dst[i] = f2bf(wih[(size_t)j * 7137 + c]);
}
__global__ __launch_bounds__(256) void cast_genw_kernel(
    const float* __restrict__ g, unsigned short* __restrict__ dst) {
  int i = blockIdx.x * 256 + threadIdx.x;           // 3407872
  if (i < 6656 * 512) {
    int nrow = i >> 9, c = i & 511;
    float v = (nrow < 6625) ? g[(size_t)nrow * 512 + c] : 0.f;
    dst[i] = f2bf(v);
  }
}
__global__ __launch_bounds__(256) void transpose_oh_kernel(
    const float* __restrict__ wih, unsigned short* __restrict__ dst) {
  __shared__ float tile[32][33];
  int t0 = blockIdx.x * 32;
  int j0 = blockIdx.y * 32;
  int c = threadIdx.x & 31;
  int r4 = threadIdx.x >> 5;
#pragma unroll
  for (int rr = 0; rr < 4; ++rr) {
    int r = r4 + rr * 8;
    int tcol = t0 + c;
    tile[r][c] = (tcol < 6625) ? wih[(size_t)(j0 + r) * 7137 + 512 + tcol] : 0.f;
  }
  __syncthreads();
#pragma unroll
  for (int rr = 0; rr < 4; ++rr) {
    int r = r4 + rr * 8;
    int trow = t0 + r;
    if (trow < 6625) dst[(size_t)trow * 1536 + j0 + c] = f2bf(tile[c][r]);
  }
}

// ---------------- D1: pp matvec + attention + ctx (one block per batch row) ----------------
__global__ __launch_bounds__(512) void attn_step_kernel(
    const unsigned short* __restrict__ proj_bf,   // [20480, 512]
    const unsigned short* __restrict__ inputs_bf, // [20480, 512]
    const unsigned short* __restrict__ h2h_bf,    // [512, 512]
    const float* __restrict__ h2h_b,              // [512]
    const float* __restrict__ score_w,            // [512]
    const unsigned short* __restrict__ h_in,      // [256, 512] (ignored when s==0)
    unsigned short* __restrict__ ctx_bf,          // [256, 512]
    int s)
{
  __shared__ float h_lds[512];
  __shared__ float pp_lds[512];
  __shared__ float e_s[80];
  __shared__ float alpha_s[80];

  const int tid = threadIdx.x;
  const int lane = tid & 63;
  const int w = tid >> 6;
  const int b = blockIdx.x;

  if (s > 0) h_lds[tid] = bf2f(h_in[b * 512 + tid]);
  __syncthreads();

  // pp[tid] = h[b] . h2h_w[tid,:] + h2h_b[tid]
  float pacc = h2h_b[tid];
  if (s > 0) {
    const unsigned short* wr = h2h_bf + (size_t)tid * 512;
#pragma unroll 4
    for (int k8 = 0; k8 < 64; ++k8) {
      union { i32x4 v; unsigned short us[8]; } u;
      u.v = *(const i32x4*)(wr + k8 * 8);
#pragma unroll
      for (int j = 0; j < 8; ++j)
        pacc = fmaf(bf2f(u.us[j]), h_lds[k8 * 8 + j], pacc);
    }
  }
  pp_lds[tid] = pacc;
  __syncthreads();

  // scores
  float ppv[8], swv[8];
#pragma unroll
  for (int j = 0; j < 8; ++j) ppv[j] = pp_lds[lane * 8 + j];
  *(float4*)&swv[0] = *(const float4*)(score_w + lane * 8);
  *(float4*)&swv[4] = *(const float4*)(score_w + lane * 8 + 4);

  for (int t = w; t < 80; t += 8) {
    union { i32x4 v; unsigned short us[8]; } u;
    u.v = *(const i32x4*)(proj_bf + (size_t)(b * 80 + t) * 512 + lane * 8);
    float acc = 0.f;
#pragma unroll
    for (int j = 0; j < 8; ++j) acc += fast_tanh(bf2f(u.us[j]) + ppv[j]) * swv[j];
#pragma unroll
    for (int m = 32; m >= 1; m >>= 1) acc += __shfl_xor(acc, m, 64);
    if (lane == 0) e_s[t] = acc;
  }
  __syncthreads();
  if (w == 0) {
    float v0 = e_s[lane];
    float v1 = (lane < 16) ? e_s[64 + lane] : -1e30f;
    float mx = fmaxf(v0, v1);
#pragma unroll
    for (int m = 32; m >= 1; m >>= 1) mx = fmaxf(mx, __shfl_xor(mx, m, 64));
    float a0 = fast_exp(v0 - mx);
    float a1 = (lane < 16) ? fast_exp(v1 - mx) : 0.f;
    float sm = a0 + a1;
#pragma unroll
    for (int m = 32; m >= 1; m >>= 1) sm += __shfl_xor(sm, m, 64);
    float inv = frcp(sm);
    alpha_s[lane] = a0 * inv;
    if (lane < 16) alpha_s[64 + lane] = a1 * inv;
  }
  __syncthreads();

  // ctx[b][tid]
  float cacc = 0.f;
  const unsigned short* ip = inputs_bf + (size_t)b * 40960;
#pragma unroll 8
  for (int t = 0; t < 80; ++t)
    cacc = fmaf(alpha_s[t], bf2f(ip[t * 512 + tid]), cacc);
  ctx_bf[(size_t)b * 512 + tid] = f2bf(cacc);
}

// ---------------- D2: [gh; gi] dual GEMM + GRU cell epilogue ----------------
// Tile: 64 rows x 96 cols (3 gates x 32 channels, gathered B-rows), BK=64, 4 waves.
// LDS staging XOR-swizzled (linear dest + inverse-swizzled source + swizzled read).
__global__ __launch_bounds__(256) void gru_step_kernel(
    const unsigned short* __restrict__ h_in,   // [256,512]
    const unsigned short* __restrict__ ctx,    // [256,512]
    const unsigned short* __restrict__ whh,    // [1536,512]
    const unsigned short* __restrict__ wihc,   // [1536,512]
    const unsigned short* __restrict__ ohT,    // [6625,1536]
    const int* __restrict__ targets,           // [256,25]
    const float* __restrict__ bih, const float* __restrict__ bhh,
    unsigned short* __restrict__ h_out,        // [256,512]
    unsigned short* __restrict__ hid_bf,       // [6400,512]
    int s)
{
  __shared__ __align__(16) char sm[49152];
  unsigned short* lAh = (unsigned short*)sm;   // [64][64] halfwords, swizzled
  unsigned short* lAc = lAh + 4096;
  unsigned short* lBw = lAh + 8192;            // [96][64]
  unsigned short* lBi = lAh + 14336;

  const int tid = threadIdx.x;
  const int lane = tid & 63;
  const int w = tid >> 6;
  const int fr = lane & 15, kg = lane >> 4;
  const int wm = w >> 1, wn = w & 1;
  const int m0 = blockIdx.y * 64;
  const int c0 = blockIdx.x * 32;

  f32x4 ag[2][3], ai[2][3];
#pragma unroll
  for (int i = 0; i < 2; ++i)
#pragma unroll
    for (int j = 0; j < 3; ++j) { ag[i][j] = 0.f; ai[i][j] = 0.f; }

  for (int kt = 0; kt < 8; ++kt) {
    const int kb = kt * 64;
    // A tiles: 512 chunks each (2/thread)
#pragma unroll
    for (int i = 0; i < 2; ++i) {
      int c = tid + i * 256;
      int row = c >> 3, k8 = c & 7;
      int sk8 = k8 ^ (row & 7);
      stage16(h_in + (size_t)(m0 + row) * 512 + kb + sk8 * 8, lAh + (i * 256 + w * 64) * 8, lane);
      stage16(ctx  + (size_t)(m0 + row) * 512 + kb + sk8 * 8, lAc + (i * 256 + w * 64) * 8, lane);
    }
    // B tiles: 768 chunks each (3/thread); gathered rows (gate g, channel c0+..)
#pragma unroll
    for (int i = 0; i < 3; ++i) {
      int c = tid + i * 256;
      int br = c >> 3, k8 = c & 7;
      int sk8 = k8 ^ (br & 7);
      int gr = (br >> 5) * 512 + c0 + (br & 31);
      stage16(whh  + (size_t)gr * 512 + kb + sk8 * 8, lBw + (i * 256 + w * 64) * 8, lane);
      stage16(wihc + (size_t)gr * 512 + kb + sk8 * 8, lBi + (i * 256 + w * 64) * 8, lane);
    }
    __syncthreads();

#pragma unroll
    for (int ks = 0; ks < 2; ++ks) {
      const int kc = ks * 4 + kg;
      i32x4 ah[2], ac[2], bw[3], bi[3];
#pragma unroll
      for (int i = 0; i < 2; ++i) {
        int r = wm * 32 + i * 16 + fr;
        int off = r * 64 + (kc ^ (r & 7)) * 8;
        ah[i] = *(const i32x4*)&lAh[off];
        ac[i] = *(const i32x4*)&lAc[off];
      }
#pragma unroll
      for (int j = 0; j < 3; ++j) {
        int r = wn * 48 + j * 16 + fr;
        int off = r * 64 + (kc ^ (r & 7)) * 8;
        bw[j] = *(const i32x4*)&lBw[off];
        bi[j] = *(const i32x4*)&lBi[off];
      }
#pragma unroll
      for (int i = 0; i < 2; ++i)
#pragma unroll
        for (int j = 0; j < 3; ++j) {
          mfma_bf16_16x16x32(ag[i][j], ah[i], bw[j]);
          mfma_bf16_16x16x32(ai[i][j], ac[i], bi[j]);
        }
    }
    __syncthreads();
  }

  // epilogue: bounce acc through LDS, then GRU cell
  float* accg = (float*)sm;        // [64][96]
  float* acci = accg + 6144;
  const int crow = (lane >> 4) * 4;
  const int ccol = lane & 15;
#pragma unroll
  for (int i = 0; i < 2; ++i)
#pragma unroll
    for (int j = 0; j < 3; ++j) {
      int col = wn * 48 + j * 16 + ccol;
#pragma unroll
      for (int r = 0; r < 4; ++r) {
        int row = wm * 32 + i * 16 + crow + r;
        accg[row * 96 + col] = ag[i][j][r];
        acci[row * 96 + col] = ai[i][j][r];
      }
    }
  __syncthreads();

#pragma unroll
  for (int e = tid; e < 2048; e += 256) {
    int row = e >> 5, cc = e & 31;
    int b = m0 + row, ch = c0 + cc;
    int tgt = targets[b * 25 + s];
    const unsigned short* oh = ohT + (size_t)tgt * 1536;
    float ghr = accg[row * 96 + cc]      + bhh[ch];
    float ghz = accg[row * 96 + 32 + cc] + bhh[512 + ch];
    float ghn = accg[row * 96 + 64 + cc] + bhh[1024 + ch];
    float gir = acci[row * 96 + cc]      + bih[ch]        + bf2f(oh[ch]);
    float giz = acci[row * 96 + 32 + cc] + bih[512 + ch]  + bf2f(oh[512 + ch]);
    float gin = acci[row * 96 + 64 + cc] + bih[1024 + ch] + bf2f(oh[1024 + ch]);
    float r_ = fast_sigmoid(gir + ghr);
    float z_ = fast_sigmoid(giz + ghz);
    float n_ = fast_tanh(gin + r_ * ghn);
    float h = (1.f - z_) * n_ + z_ * bf2f(h_in[(size_t)b * 512 + ch]);
    unsigned short hb = f2bf(h);
    h_out[(size_t)b * 512 + ch] = hb;
    hid_bf[((size_t)b * 25 + s) * 512 + ch] = hb;
  }
}

extern "C" void kernel_launch(void* const* d_in, const int* in_sizes, int n_in,
                              void* d_out, int out_size, void* d_ws, size_t ws_size,
                              hipStream_t stream) {
  (void)in_sizes; (void)n_in; (void)out_size; (void)ws_size;
  const float* inputs  = (const float*)d_in[0];
  const int*   targets = (const int*)d_in[1];
  const float* i2h_w   = (const float*)d_in[3];
  const float* h2h_w   = (const float*)d_in[4];
  const float* h2h_b   = (const float*)d_in[5];
  const float* score_w = (const float*)d_in[6];
  const float* gru_wih = (const float*)d_in[7];
  const float* gru_whh = (const float*)d_in[8];
  const float* gru_bih = (const float*)d_in[9];
  const float* gru_bhh = (const float*)d_in[10];
  const float* gen_w   = (const float*)d_in[11];
  const float* gen_b   = (const float*)d_in[12];
  float* out = (float*)d_out;

  char* ws = (char*)d_ws;
  size_t off = 0;
  auto alloc = [&](size_t bytes) {
    char* p = ws + off;
    off += (bytes + 255) & ~(size_t)255;
    return p;
  };
  unsigned short* inputs_bf = (unsigned short*)alloc(10485760ull * 2);
  unsigned short* proj_bf   = (unsigned short*)alloc(10485760ull * 2);
  unsigned short* i2h_bf    = (unsigned short*)alloc(262144ull * 2);
  unsigned short* h2h_bf    = (unsigned short*)alloc(262144ull * 2);
  unsigned short* whh_bf    = (unsigned short*)alloc(786432ull * 2);
  unsigned short* wihc_bf   = (unsigned short*)alloc(786432ull * 2);
  unsigned short* ohT_bf    = (unsigned short*)alloc(10176000ull * 2);
  unsigned short* genw_bf   = (unsigned short*)alloc(3407872ull * 2);
  unsigned short* ctx_bf    = (unsigned short*)alloc(131072ull * 2);
  unsigned short* hbuf0     = (unsigned short*)alloc(131072ull * 2);
  unsigned short* hbuf1     = (unsigned short*)alloc(131072ull * 2);
  unsigned short* hid_bf    = (unsigned short*)alloc(3276800ull * 2);

  // prologue
  cast_bf16_kernel<<<10240, 256, 0, stream>>>(inputs, inputs_bf, 2621440);
  cast_bf16_kernel<<<256, 256, 0, stream>>>(i2h_w, i2h_bf, 65536);
  cast_bf16_kernel<<<256, 256, 0, stream>>>(h2h_w, h2h_bf, 65536);
  cast_bf16_kernel<<<768, 256, 0, stream>>>(gru_whh, whh_bf, 196608);
  cast_wihc_kernel<<<3072, 256, 0, stream>>>(gru_wih, wihc_bf);
  transpose_oh_kernel<<<dim3(208, 48), 256, 0, stream>>>(gru_wih, ohT_bf);
  cast_genw_kernel<<<13312, 256, 0, stream>>>(gen_w, genw_bf);
  // proj = inputs @ i2h_w^T  [20480, 512]
  gemm_bf16out_kernel<<<dim3(4, 160), 256, 0, stream>>>(inputs_bf, i2h_bf, proj_bf, 512, 512);
  hipMemsetAsync(hbuf0, 0, 131072 * 2, stream);

  // 25 steps, 2 dispatches each; h ping-pongs between hbuf0/hbuf1
  unsigned short* hb[2] = {hbuf0, hbuf1};
  for (int s = 0; s < 25; ++s) {
    attn_step_kernel<<<256, 512, 0, stream>>>(
        proj_bf, inputs_bf, h2h_bf, h2h_b, score_w, hb[s & 1], ctx_bf, s);
    gru_step_kernel<<<dim3(16, 4), 256, 0, stream>>>(
        hb[s & 1], ctx_bf, whh_bf, wihc_bf, ohT_bf, targets,
        gru_bih, gru_bhh, hb[(s + 1) & 1], hid_bf, s);
  }

  // epilogue: probs = hiddens @ gen_w^T + gen_b
  gemm_f32bias_kernel<<<dim3(52, 50), 256, 0, stream>>>(hid_bf, genw_bf, out, gen_b, 512, 6625, 6625);
}